// Round 13
// baseline (3137.916 us; speedup 1.0000x reference)
//
#include <hip/hip_runtime.h>
#include <hip/hip_fp16.h>
#include <cstdint>
#include <cstddef>

#define TT 512
#define BB 64
#define EE 256
#define HH 256
#define G4 1024   // 4*H
#define DD 512    // 2*H
#define NCLS 5
#define CH 64     // time-steps per chunk
#define NCH (TT / CH)

typedef _Float16 half8 __attribute__((ext_vector_type(8)));
typedef float f32x4 __attribute__((ext_vector_type(4)));

// Workspace layout (bytes). Total = 54,140,928 B (~51.6 MB).
#define OFF_XGF   0ull                 // 8,388,608  fp16 frag-ordered [CH*4][64][256]
#define OFF_XGB   8388608ull           // 8,388,608
#define OFF_OUTB  16777216ull          // 33,554,432 fp16 [512][64][512]
#define OFF_WHHF  50331648ull          // 1,048,576  fp16 frag [2][64 pf][8 ks][64 lane][8 r]
#define OFF_WIHF  51380224ull          // 1,048,576  fp16 frag
#define OFF_BIAS  52428800ull          // 8,192      f32 [2][1024] (pcol-permuted)
#define OFF_HST   52436992ull          // 131,072    f32 [2][64][256]
#define OFF_CST   52568064ull          // 131,072
#define OFF_LOG   52699136ull          // 131,072    f32 [512][64]
#define OFF_ATT   52830208ull          // 131,072
#define OFF_HEX   52961280ull          // (unused this round)
#define OFF_FLG   53092352ull          // 524,288: stamped hex u32 [8 grp][2 par][4 ug][16 r][64 u] = 256KB used
#define OFF_WWF   53616640ull          // 524,288  fp16 frag [32 cf][16 ks][64 lane][8 r]

__device__ __forceinline__ f32x4 mfma16(half8 a, half8 b, f32x4 c) {
  return __builtin_amdgcn_mfma_f32_16x16x32_f16(a, b, c, 0, 0, 0);
}
__device__ __forceinline__ float tanh_(float x) {
  float e = __expf(2.f * x);
  return 1.f - __fdividef(2.f, e + 1.f);
}
__device__ __forceinline__ f32x4 shflx4(f32x4 v, int mask) {
  f32x4 r;
  r[0] = __shfl_xor(v[0], mask, 64);
  r[1] = __shfl_xor(v[1], mask, 64);
  r[2] = __shfl_xor(v[2], mask, 64);
  r[3] = __shfl_xor(v[3], mask, 64);
  return r;
}

// h LDS swizzle: row br, unit u -> ushort index
#define HSWZ(br, u) ((((br) * 256) + (u)) ^ (((br) & 7) << 3))

// ---------------------------------------------------------------------------
// Fragment-order the weights (fp16), GATE-PERMUTED columns (unchanged).
// ---------------------------------------------------------------------------
__global__ __launch_bounds__(256) void make_frags(
    const float* __restrict__ WhhF, const float* __restrict__ WhhB,
    const float* __restrict__ WihF, const float* __restrict__ WihB,
    __half* __restrict__ whhfrag, __half* __restrict__ wihfrag)
{
  int idx = blockIdx.x * 256 + threadIdx.x;   // 0 .. 2^20-1
  int r = idx & 7, lane = (idx >> 3) & 63, ks = (idx >> 9) & 7;
  int mm = lane & 15;
  int k = ks * 32 + (lane >> 4) * 8 + r;
  if (idx < (1 << 19)) {
    int pf = (idx >> 12) & 63, d = (idx >> 18) & 1;
    const float* W = d ? WhhB : WhhF;
    int g = (mm & 3) * 256 + pf * 4 + (mm >> 2);
    whhfrag[idx] = __float2half(W[(size_t)g * HH + k]);
  } else {
    int e = idx - (1 << 19);
    int pf = (e >> 12) & 63, d = (e >> 18) & 1;
    const float* W = d ? WihB : WihF;
    int g = (mm & 3) * 256 + pf * 4 + (mm >> 2);
    wihfrag[e] = __float2half(W[(size_t)g * EE + k]);
  }
}

// wwfrag[cf][ks][lane][r] = W_word[k][e], e = cf*16+(lane&15), k = ks*32+(lane>>4)*8+r
__global__ __launch_bounds__(256) void make_wwfrag(
    const float* __restrict__ Ww, __half* __restrict__ wwfrag)
{
  int idx = blockIdx.x * 256 + threadIdx.x;   // 0..262143
  int r = idx & 7, lane = (idx >> 3) & 63, ks = (idx >> 9) & 15, cf = idx >> 13;
  int e = cf * 16 + (lane & 15);
  int k = ks * 32 + (lane >> 4) * 8 + r;
  wwfrag[idx] = __float2half(Ww[(size_t)k * DD + e]);
}

__global__ __launch_bounds__(256) void bias_prep(
    const float* __restrict__ bihF, const float* __restrict__ bhhF,
    const float* __restrict__ bihB, const float* __restrict__ bhhB,
    float* __restrict__ bias)
{
  int i = blockIdx.x * 256 + threadIdx.x;    // 0..2047
  int d = i >> 10, pcol = i & 1023;
  int g = (pcol & 3) * 256 + (pcol >> 2);
  bias[i] = (d ? bihB : bihF)[g] + (d ? bhhB : bhhF)[g];
}

// ---------------------------------------------------------------------------
// xg chunk via MFMA, output fragment-ordered (unchanged, known-good).
// ---------------------------------------------------------------------------
__global__ __launch_bounds__(256) void xg_mfma(
    int c, const int* __restrict__ embed, const float* __restrict__ emb,
    const __half* __restrict__ wihfrag, const float* __restrict__ biassum,
    __half* __restrict__ xgF, __half* __restrict__ xgB)
{
  const int d = blockIdx.z, ls = blockIdx.x, gblk = blockIdx.y;
  int t = c * CH + ls;
  if (d) t = TT - 1 - t;
  __half* xg = d ? xgB : xgF;
  const int tid = threadIdx.x, w = tid >> 6, l = tid & 63;

  __shared__ int idx[64];
  __shared__ unsigned short xs[64 * 256];   // 32 KB, swizzled fp16 x

  if (tid < 64) idx[tid] = embed[t * BB + tid];
  __syncthreads();

  {
    const int rr = tid >> 2, cq = (tid & 3) * 64;
    const float* src = emb + (size_t)idx[rr] * EE + cq;
#pragma unroll
    for (int j = 0; j < 8; ++j) {
      float4 a = *(const float4*)(src + j * 8);
      float4 b = *(const float4*)(src + j * 8 + 4);
      half8 hv;
      hv[0] = (_Float16)a.x; hv[1] = (_Float16)a.y; hv[2] = (_Float16)a.z; hv[3] = (_Float16)a.w;
      hv[4] = (_Float16)b.x; hv[5] = (_Float16)b.y; hv[6] = (_Float16)b.z; hv[7] = (_Float16)b.w;
      int hidx = (rr * 256 + cq + j * 8) ^ ((rr & 7) << 3);
      *(half8*)&xs[hidx] = hv;
    }
  }
  __syncthreads();

  const __half* bfb = wihfrag + (size_t)((d * 64 + gblk * 4) * 8) * 512 + l * 8;
  half8 Bf[4][8];
#pragma unroll
  for (int ct = 0; ct < 4; ++ct)
#pragma unroll
    for (int ks = 0; ks < 8; ++ks)
      Bf[ct][ks] = *(const half8*)(bfb + (ct * 8 + ks) * 512);

  f32x4 acc[4];
#pragma unroll
  for (int ct = 0; ct < 4; ++ct) {
    float bv = biassum[d * 1024 + gblk * 64 + ct * 16 + (l & 15)];
    acc[ct][0] = bv; acc[ct][1] = bv; acc[ct][2] = bv; acc[ct][3] = bv;
  }

  const int arow = w * 16 + (l & 15);
#pragma unroll
  for (int ks = 0; ks < 8; ++ks) {
    int hidx = (arow * 256 + ks * 32 + (l >> 4) * 8) ^ ((arow & 7) << 3);
    half8 af = *(const half8*)&xs[hidx];
#pragma unroll
    for (int ct = 0; ct < 4; ++ct)
      acc[ct] = mfma16(af, Bf[ct][ks], acc[ct]);
  }

#pragma unroll
  for (int ct = 0; ct < 4; ++ct) {
    ushort4 sv;
    sv.x = __half_as_ushort(__float2half(acc[ct][0]));
    sv.y = __half_as_ushort(__float2half(acc[ct][1]));
    sv.z = __half_as_ushort(__float2half(acc[ct][2]));
    sv.w = __half_as_ushort(__float2half(acc[ct][3]));
    size_t base = ((size_t)(ls * 4 + w) * 64 + (gblk * 4 + ct)) * 256 + l * 4;
    *(ushort4*)((unsigned short*)xg + base) = sv;
  }
}

// ---------------------------------------------------------------------------
// Distributed persistent LSTM scan, v7: STAMPED-DATA exchange (flagless).
// grid (32): id = ug*8 + grp, grp = d*4+bg (4 exchange partners share grp).
// Published word = (stamp<<16)|h_fp16 (stamp = global step +1, unique per
// parity-slab reuse). Consumers spin on the data words directly: validity
// arrives WITH payload -> one L3 round-trip instead of three. No vmcnt
// drain, no flags. Rest identical to r12's scan_dist4.
// ---------------------------------------------------------------------------
__global__ __launch_bounds__(512, 2) void scan_dist6(
    int c, const __half* __restrict__ xgF, const __half* __restrict__ xgB,
    const __half* __restrict__ whhfrag,
    const float* __restrict__ hin, const float* __restrict__ cin,
    float* __restrict__ hstate, float* __restrict__ cstate,
    __half* __restrict__ outb, unsigned int* __restrict__ hexs)
{
  const int id = blockIdx.x;
  const int ug = id >> 3, grp = id & 7;
  const int d = grp >> 2, bg = grp & 3;
  const int tid = threadIdx.x, w = tid >> 6, l = tid & 63;
  const int m = l & 15, qr = l >> 4, q = m & 3, ul = m >> 2;
  const unsigned short* xg = (const unsigned short*)(d ? xgB : xgF);

  __shared__ unsigned short hb0[16 * 256];   // 8 KB (double buffer)
  __shared__ unsigned short hb1[16 * 256];   // 8 KB

  const int pf0 = ug * 16 + w * 2;

  // Whh fragments, VGPR-resident (64 VGPR)
  half8 Wf[2][8];
#pragma unroll
  for (int cf = 0; cf < 2; ++cf)
#pragma unroll
    for (int ks = 0; ks < 8; ++ks)
      Wf[cf][ks] = *(const half8*)(whhfrag +
          ((size_t)(d * 64 + pf0 + cf) * 8 + ks) * 512 + l * 8);

  // stage h_in into hb0, c_in into regs
#pragma unroll
  for (int i = 0; i < 8; ++i) {
    int idx = i * 512 + tid;
    int r = idx >> 8, u = idx & 255;
    hb0[HSWZ(r, u)] = __half_as_ushort(
        __float2half(hin[(size_t)(d * BB + bg * 16 + r) * HH + u]));
  }
  float cst[2][4];
#pragma unroll
  for (int cf = 0; cf < 2; ++cf) {
    int U = (pf0 + cf) * 4 + ul;
#pragma unroll
    for (int j = 0; j < 4; ++j)
      cst[cf][j] = cin[(size_t)(d * BB + bg * 16 + qr * 4 + j) * HH + U];
  }
  __syncthreads();

  int afo[8];
#pragma unroll
  for (int ks = 0; ks < 8; ++ks) afo[ks] = HSWZ(m, ks * 32 + qr * 8);
  const int kso0 = ug * 2, kso1 = ug * 2 + 1;

  const unsigned short* xp = xg + ((size_t)bg * 64 + pf0) * 256 + l * 4;
  const float actB = (q == 2) ? 2.f : 1.f;

  // prologue: C-init + own-ks for step 0 (reads hb0)
  f32x4 acc[2];
  {
    ushort4 xv0[2];
#pragma unroll
    for (int cf = 0; cf < 2; ++cf) xv0[cf] = *(const ushort4*)(xp + cf * 256);
#pragma unroll
    for (int cf = 0; cf < 2; ++cf) {
      acc[cf][0] = __half2float(__ushort_as_half(xv0[cf].x));
      acc[cf][1] = __half2float(__ushort_as_half(xv0[cf].y));
      acc[cf][2] = __half2float(__ushort_as_half(xv0[cf].z));
      acc[cf][3] = __half2float(__ushort_as_half(xv0[cf].w));
    }
    half8 ao0 = *(const half8*)&hb0[afo[kso0]];
    half8 ao1 = *(const half8*)&hb0[afo[kso1]];
#pragma unroll
    for (int cf = 0; cf < 2; ++cf) {
      acc[cf] = mfma16(ao0, Wf[cf][kso0], acc[cf]);
      acc[cf] = mfma16(ao1, Wf[cf][kso1], acc[cf]);
    }
  }
  ushort4 xv[2];   // xg(ls+1)
#pragma unroll
  for (int cf = 0; cf < 2; ++cf)
    xv[cf] = *(const ushort4*)(xp + (size_t)65536 + cf * 256);

  int p = 0;
  for (int ls = 0; ls < CH; ++ls) {
    unsigned short* cur = p ? hb1 : hb0;
    unsigned short* nxt = p ? hb0 : hb1;
    int tA = c * CH + ls;
    if (d) tA = TT - 1 - tA;
    // stamped slab for this (grp, parity): [4 ug][16 r][64 u] u32
    unsigned int* hx = hexs + (size_t)(grp * 2 + (ls & 1)) * 4096;
    const unsigned int stamp = (unsigned int)(c * CH + ls + 1);

    // peer A-frags from cur (no barrier needed: writes go to nxt)
    half8 afp[6];
#pragma unroll
    for (int i = 0; i < 6; ++i) {
      int ks = i + (i >= kso0 ? 2 : 0);
      afp[i] = *(const half8*)&cur[afo[ks]];
    }
#pragma unroll
    for (int i = 0; i < 6; ++i) {
      int ks = i + (i >= kso0 ? 2 : 0);
#pragma unroll
      for (int cf = 0; cf < 2; ++cf)
        acc[cf] = mfma16(afp[i], Wf[cf][ks], acc[cf]);
    }

    // slim epilogue; q==0 lanes own the combined result; publish stamped b32
#pragma unroll
    for (int cf = 0; cf < 2; ++cf) {
      f32x4 a0;
#pragma unroll
      for (int jj = 0; jj < 4; ++jj) {
        float e = __expf(actB * acc[cf][jj]);
        a0[jj] = 1.f - __fdividef(actB, e + 1.f);
      }
      f32x4 a1 = shflx4(a0, 1);
      f32x4 a2 = shflx4(a0, 2);
      f32x4 a3 = shflx4(a0, 3);
      const int U = (pf0 + cf) * 4 + ul;
      const int uloc = (w * 2 + cf) * 4 + ul;   // local unit 0..63 in ug slab
#pragma unroll
      for (int jj = 0; jj < 4; ++jj) {
        float cn = a1[jj] * cst[cf][jj] + a0[jj] * a2[jj];
        cst[cf][jj] = cn;
        float e2 = __expf(2.f * cn);
        float hv = a3[jj] * (1.f - __fdividef(2.f, e2 + 1.f));
        if (q == 0) {
          unsigned short hu = __half_as_ushort(__float2half(hv));
          int r = qr * 4 + jj;
          nxt[HSWZ(r, U)] = hu;
          __hip_atomic_store(&hx[(ug * 16 + r) * 64 + uloc],
                             (stamp << 16) | (unsigned int)hu,
                             __ATOMIC_RELAXED, __HIP_MEMORY_SCOPE_AGENT);
        }
      }
    }
    __syncthreads();   // B_b: nxt own slice complete in LDS

    // ---- overlapped, peer-independent work ----
    {
      const int pr = tid >> 5, uL2 = (tid & 31) * 2;
      const int u = ug * 64 + uL2;
      *(unsigned int*)&outb[((size_t)tA * BB + bg * 16 + pr) * DD + d * HH + u] =
          *(const unsigned int*)&nxt[HSWZ(pr, u)];
    }
#pragma unroll
    for (int cf = 0; cf < 2; ++cf) {
      acc[cf][0] = __half2float(__ushort_as_half(xv[cf].x));
      acc[cf][1] = __half2float(__ushort_as_half(xv[cf].y));
      acc[cf][2] = __half2float(__ushort_as_half(xv[cf].z));
      acc[cf][3] = __half2float(__ushort_as_half(xv[cf].w));
    }
    {
      half8 ao0 = *(const half8*)&nxt[afo[kso0]];
      half8 ao1 = *(const half8*)&nxt[afo[kso1]];
#pragma unroll
      for (int cf = 0; cf < 2; ++cf) {
        acc[cf] = mfma16(ao0, Wf[cf][kso0], acc[cf]);
        acc[cf] = mfma16(ao1, Wf[cf][kso1], acc[cf]);
      }
    }
    {
      int lsn = (ls + 2 < CH) ? ls + 2 : CH - 1;
      const unsigned short* xn = xp + (size_t)lsn * 65536;
#pragma unroll
      for (int cf = 0; cf < 2; ++cf)
        xv[cf] = *(const ushort4*)(xn + cf * 256);
    }

    // ---- pull 3 peer slices: spin on the stamped data words directly ----
#pragma unroll
    for (int rep = 0; rep < 6; ++rep) {
      int idx = rep * 512 + tid;          // 0..3071
      int pi = idx >> 10, wi = idx & 1023;
      int peer = pi + (pi >= ug ? 1 : 0);
      int r = wi >> 6, uloc = wi & 63;
      unsigned int v;
      do {
        v = __hip_atomic_load(&hx[(peer * 16 + r) * 64 + uloc],
                              __ATOMIC_RELAXED, __HIP_MEMORY_SCOPE_AGENT);
      } while ((v >> 16) != stamp);
      nxt[HSWZ(r, peer * 64 + uloc)] = (unsigned short)(v & 0xffff);
    }
    __syncthreads();   // B_d: nxt = h(ls+1) complete
    p ^= 1;
  }

  // final states (h in hb[p], c in regs)
  {
    unsigned short* fin = p ? hb1 : hb0;
#pragma unroll
    for (int i = 0; i < 8; ++i) {
      int idx = i * 512 + tid;
      int r = idx >> 8, u = idx & 255;
      hstate[(size_t)(d * BB + bg * 16 + r) * HH + u] =
          __half2float(__ushort_as_half(fin[HSWZ(r, u)]));
    }
  }
  if (q == 0) {
#pragma unroll
    for (int cf = 0; cf < 2; ++cf) {
      int U = (pf0 + cf) * 4 + ul;
#pragma unroll
      for (int j = 0; j < 4; ++j)
        cstate[(size_t)(d * BB + bg * 16 + qr * 4 + j) * HH + U] = cst[cf][j];
    }
  }
}

// ---------------------------------------------------------------------------
// squish+logits via MFMA (validated r11: absmax unchanged at 4.88e-4)
// ---------------------------------------------------------------------------
__global__ __launch_bounds__(256, 1) void squish_mfma(
    const __half* __restrict__ outb, const __half* __restrict__ wwfrag,
    const float* __restrict__ bw, const float* __restrict__ proj,
    float* __restrict__ logits)
{
  const int r0 = blockIdx.x * 64;
  const int tid = threadIdx.x, w = tid >> 6, l = tid & 63;
  const int m = l & 15, qr = l >> 4;

  f32x4 acc[32];
#pragma unroll
  for (int cf = 0; cf < 32; ++cf) {
    acc[cf][0] = 0.f; acc[cf][1] = 0.f; acc[cf][2] = 0.f; acc[cf][3] = 0.f;
  }

  const unsigned short* arow =
      (const unsigned short*)outb + (size_t)(r0 + w * 16 + m) * DD + qr * 8;
  const __half* bfb = wwfrag + l * 8;

#pragma unroll
  for (int ks = 0; ks < 16; ++ks) {
    half8 a = *(const half8*)(arow + ks * 32);
#pragma unroll
    for (int cf = 0; cf < 32; ++cf) {
      half8 b = *(const half8*)(bfb + (size_t)(cf * 16 + ks) * 512);
      acc[cf] = mfma16(a, b, acc[cf]);
    }
  }

  float partial[4] = {0.f, 0.f, 0.f, 0.f};
#pragma unroll
  for (int cf = 0; cf < 32; ++cf) {
    int e = cf * 16 + m;
    float bwv = bw[e], pv = proj[e];
#pragma unroll
    for (int r = 0; r < 4; ++r)
      partial[r] += tanh_(acc[cf][r] + bwv) * pv;
  }
#pragma unroll
  for (int mask = 1; mask < 16; mask <<= 1)
#pragma unroll
    for (int r = 0; r < 4; ++r)
      partial[r] += __shfl_xor(partial[r], mask, 64);
  if (m == 0) {
#pragma unroll
    for (int r = 0; r < 4; ++r)
      logits[r0 + w * 16 + qr * 4 + r] = partial[r];
  }
}

// ---------------------------------------------------------------------------
__global__ __launch_bounds__(256) void softmax_t(const float* __restrict__ logits,
                                                 float* __restrict__ attn)
{
  const int b = blockIdx.x;
  const int tid = threadIdx.x;
  __shared__ float sm[256];
  float v0 = logits[tid * BB + b];
  float v1 = logits[(tid + 256) * BB + b];
  sm[tid] = fmaxf(v0, v1);
  __syncthreads();
  for (int s = 128; s > 0; s >>= 1) {
    if (tid < s) sm[tid] = fmaxf(sm[tid], sm[tid + s]);
    __syncthreads();
  }
  float M = sm[0];
  __syncthreads();
  float e0 = expf(v0 - M), e1 = expf(v1 - M);
  sm[tid] = e0 + e1;
  __syncthreads();
  for (int s = 128; s > 0; s >>= 1) {
    if (tid < s) sm[tid] += sm[tid + s];
    __syncthreads();
  }
  float inv = 1.f / sm[0];
  attn[tid * BB + b] = e0 * inv;
  attn[(tid + 256) * BB + b] = e1 * inv;
}

// ---------------------------------------------------------------------------
__global__ __launch_bounds__(512) void vec_final(
    const __half* __restrict__ outb, const float* __restrict__ attn,
    const float* __restrict__ linW, const float* __restrict__ linb,
    float* __restrict__ y)
{
  const int b = blockIdx.x;
  const int d = threadIdx.x;
  float acc = 0.f;
  for (int t = 0; t < TT; ++t)
    acc += attn[t * BB + b] * __half2float(outb[((size_t)t * BB + b) * DD + d]);
  __shared__ float red[512];
  for (int cls = 0; cls < NCLS; ++cls) {
    red[d] = acc * linW[cls * DD + d];
    __syncthreads();
    for (int s = 256; s > 0; s >>= 1) {
      if (d < s) red[d] += red[d + s];
      __syncthreads();
    }
    if (d == 0) y[b * NCLS + cls] = red[0] + linb[cls];
    __syncthreads();
  }
}

// ---------------------------------------------------------------------------
extern "C" void kernel_launch(void* const* d_in, const int* in_sizes, int n_in,
                              void* d_out, int out_size, void* d_ws, size_t ws_size,
                              hipStream_t stream) {
  const int*   embed     = (const int*)d_in[0];
  const float* h0        = (const float*)d_in[1];
  const float* c0        = (const float*)d_in[2];
  const float* emb_table = (const float*)d_in[3];
  const float* Wih_f     = (const float*)d_in[4];
  const float* Whh_f     = (const float*)d_in[5];
  const float* bih_f     = (const float*)d_in[6];
  const float* bhh_f     = (const float*)d_in[7];
  const float* Wih_b     = (const float*)d_in[8];
  const float* Whh_b     = (const float*)d_in[9];
  const float* bih_b     = (const float*)d_in[10];
  const float* bhh_b     = (const float*)d_in[11];
  const float* W_word    = (const float*)d_in[12];
  const float* b_word    = (const float*)d_in[13];
  const float* proj_word = (const float*)d_in[14];
  const float* lin_W     = (const float*)d_in[15];
  const float* lin_b     = (const float*)d_in[16];

  char* ws = (char*)d_ws;
  __half* xgF     = (__half*)(ws + OFF_XGF);
  __half* xgB     = (__half*)(ws + OFF_XGB);
  __half* outb    = (__half*)(ws + OFF_OUTB);
  __half* whhfrag = (__half*)(ws + OFF_WHHF);
  __half* wihfrag = (__half*)(ws + OFF_WIHF);
  float*  biassum = (float*)(ws + OFF_BIAS);
  float*  hstate  = (float*)(ws + OFF_HST);
  float*  cstate  = (float*)(ws + OFF_CST);
  float*  logits  = (float*)(ws + OFF_LOG);
  float*  attn    = (float*)(ws + OFF_ATT);
  unsigned int* hexs = (unsigned int*)(ws + OFF_FLG);
  __half* wwfrag  = (__half*)(ws + OFF_WWF);

  // zero the stamped-hex slabs every launch (stale stamps from prior launches
  // must not match; deterministic; graph-capturable)
  hipMemsetAsync(hexs, 0, 262144, stream);

  make_frags<<<4096, 256, 0, stream>>>(Whh_f, Whh_b, Wih_f, Wih_b, whhfrag, wihfrag);
  make_wwfrag<<<1024, 256, 0, stream>>>(W_word, wwfrag);
  bias_prep<<<8, 256, 0, stream>>>(bih_f, bhh_f, bih_b, bhh_b, biassum);

  for (int c = 0; c < NCH; ++c) {
    xg_mfma<<<dim3(CH, 16, 2), 256, 0, stream>>>(c, embed, emb_table,
        wihfrag, biassum, xgF, xgB);
    const float* hin = (c == 0) ? h0 : hstate;
    const float* cin = (c == 0) ? c0 : cstate;
    scan_dist6<<<dim3(32), 512, 0, stream>>>(c, xgF, xgB, whhfrag,
        hin, cin, hstate, cstate, outb, hexs);
  }

  squish_mfma<<<512, 256, 0, stream>>>(outb, wwfrag, b_word, proj_word, logits);
  softmax_t<<<64, 256, 0, stream>>>(logits, attn);
  vec_final<<<64, 512, 0, stream>>>(outb, attn, lin_W, lin_b, (float*)d_out);
}

// Round 14
// 2915.092 us; speedup vs baseline: 1.0764x; 1.0764x over previous
//
#include <hip/hip_runtime.h>
#include <hip/hip_fp16.h>
#include <cstdint>
#include <cstddef>

#define TT 512
#define BB 64
#define EE 256
#define HH 256
#define G4 1024   // 4*H
#define DD 512    // 2*H
#define NCLS 5
#define CH 64     // time-steps per chunk
#define NCH (TT / CH)

typedef _Float16 half8 __attribute__((ext_vector_type(8)));
typedef float f32x4 __attribute__((ext_vector_type(4)));

// Workspace layout (bytes). Total = 54,140,928 B (~51.6 MB).
#define OFF_XGF   0ull                 // 8,388,608  fp16 frag-ordered [CH*4][64][256]
#define OFF_XGB   8388608ull           // 8,388,608
#define OFF_OUTB  16777216ull          // 33,554,432 fp16 [512][64][512]
#define OFF_WHHF  50331648ull          // 1,048,576  fp16 frag [2][64 pf][8 ks][64 lane][8 r]
#define OFF_WIHF  51380224ull          // 1,048,576  fp16 frag
#define OFF_BIAS  52428800ull          // 8,192      f32 [2][1024] (pcol-permuted)
#define OFF_HST   52436992ull          // 131,072    f32 [2][64][256]
#define OFF_CST   52568064ull          // 131,072
#define OFF_LOG   52699136ull          // 131,072    f32 [512][64]
#define OFF_ATT   52830208ull          // 131,072
#define OFF_HEX   52961280ull          // 131,072    ull [8 grp][2 par][256 U][4 rq]
#define OFF_FLG   53092352ull          // 524,288    int [8 grp][8 c][64 ls][32]
#define OFF_WWF   53616640ull          // 524,288    fp16 frag [32 cf][16 ks][64 lane][8 r]

__device__ __forceinline__ f32x4 mfma16(half8 a, half8 b, f32x4 c) {
  return __builtin_amdgcn_mfma_f32_16x16x32_f16(a, b, c, 0, 0, 0);
}
__device__ __forceinline__ float tanh_(float x) {
  float e = __expf(2.f * x);
  return 1.f - __fdividef(2.f, e + 1.f);
}
__device__ __forceinline__ f32x4 shflx4(f32x4 v, int mask) {
  f32x4 r;
  r[0] = __shfl_xor(v[0], mask, 64);
  r[1] = __shfl_xor(v[1], mask, 64);
  r[2] = __shfl_xor(v[2], mask, 64);
  r[3] = __shfl_xor(v[3], mask, 64);
  return r;
}

// h LDS swizzle: row br, unit u -> ushort index
#define HSWZ(br, u) ((((br) * 256) + (u)) ^ (((br) & 7) << 3))

// ---------------------------------------------------------------------------
// Fragment-order the weights (fp16), GATE-PERMUTED columns (unchanged).
// ---------------------------------------------------------------------------
__global__ __launch_bounds__(256) void make_frags(
    const float* __restrict__ WhhF, const float* __restrict__ WhhB,
    const float* __restrict__ WihF, const float* __restrict__ WihB,
    __half* __restrict__ whhfrag, __half* __restrict__ wihfrag)
{
  int idx = blockIdx.x * 256 + threadIdx.x;   // 0 .. 2^20-1
  int r = idx & 7, lane = (idx >> 3) & 63, ks = (idx >> 9) & 7;
  int mm = lane & 15;
  int k = ks * 32 + (lane >> 4) * 8 + r;
  if (idx < (1 << 19)) {
    int pf = (idx >> 12) & 63, d = (idx >> 18) & 1;
    const float* W = d ? WhhB : WhhF;
    int g = (mm & 3) * 256 + pf * 4 + (mm >> 2);
    whhfrag[idx] = __float2half(W[(size_t)g * HH + k]);
  } else {
    int e = idx - (1 << 19);
    int pf = (e >> 12) & 63, d = (e >> 18) & 1;
    const float* W = d ? WihB : WihF;
    int g = (mm & 3) * 256 + pf * 4 + (mm >> 2);
    wihfrag[e] = __float2half(W[(size_t)g * EE + k]);
  }
}

// wwfrag[cf][ks][lane][r] = W_word[k][e], e = cf*16+(lane&15), k = ks*32+(lane>>4)*8+r
__global__ __launch_bounds__(256) void make_wwfrag(
    const float* __restrict__ Ww, __half* __restrict__ wwfrag)
{
  int idx = blockIdx.x * 256 + threadIdx.x;   // 0..262143
  int r = idx & 7, lane = (idx >> 3) & 63, ks = (idx >> 9) & 15, cf = idx >> 13;
  int e = cf * 16 + (lane & 15);
  int k = ks * 32 + (lane >> 4) * 8 + r;
  wwfrag[idx] = __float2half(Ww[(size_t)k * DD + e]);
}

__global__ __launch_bounds__(256) void bias_prep(
    const float* __restrict__ bihF, const float* __restrict__ bhhF,
    const float* __restrict__ bihB, const float* __restrict__ bhhB,
    float* __restrict__ bias)
{
  int i = blockIdx.x * 256 + threadIdx.x;    // 0..2047
  int d = i >> 10, pcol = i & 1023;
  int g = (pcol & 3) * 256 + (pcol >> 2);
  bias[i] = (d ? bihB : bihF)[g] + (d ? bhhB : bhhF)[g];
}

// ---------------------------------------------------------------------------
// xg chunk via MFMA, output fragment-ordered (unchanged, known-good).
// ---------------------------------------------------------------------------
__global__ __launch_bounds__(256) void xg_mfma(
    int c, const int* __restrict__ embed, const float* __restrict__ emb,
    const __half* __restrict__ wihfrag, const float* __restrict__ biassum,
    __half* __restrict__ xgF, __half* __restrict__ xgB)
{
  const int d = blockIdx.z, ls = blockIdx.x, gblk = blockIdx.y;
  int t = c * CH + ls;
  if (d) t = TT - 1 - t;
  __half* xg = d ? xgB : xgF;
  const int tid = threadIdx.x, w = tid >> 6, l = tid & 63;

  __shared__ int idx[64];
  __shared__ unsigned short xs[64 * 256];   // 32 KB, swizzled fp16 x

  if (tid < 64) idx[tid] = embed[t * BB + tid];
  __syncthreads();

  {
    const int rr = tid >> 2, cq = (tid & 3) * 64;
    const float* src = emb + (size_t)idx[rr] * EE + cq;
#pragma unroll
    for (int j = 0; j < 8; ++j) {
      float4 a = *(const float4*)(src + j * 8);
      float4 b = *(const float4*)(src + j * 8 + 4);
      half8 hv;
      hv[0] = (_Float16)a.x; hv[1] = (_Float16)a.y; hv[2] = (_Float16)a.z; hv[3] = (_Float16)a.w;
      hv[4] = (_Float16)b.x; hv[5] = (_Float16)b.y; hv[6] = (_Float16)b.z; hv[7] = (_Float16)b.w;
      int hidx = (rr * 256 + cq + j * 8) ^ ((rr & 7) << 3);
      *(half8*)&xs[hidx] = hv;
    }
  }
  __syncthreads();

  const __half* bfb = wihfrag + (size_t)((d * 64 + gblk * 4) * 8) * 512 + l * 8;
  half8 Bf[4][8];
#pragma unroll
  for (int ct = 0; ct < 4; ++ct)
#pragma unroll
    for (int ks = 0; ks < 8; ++ks)
      Bf[ct][ks] = *(const half8*)(bfb + (ct * 8 + ks) * 512);

  f32x4 acc[4];
#pragma unroll
  for (int ct = 0; ct < 4; ++ct) {
    float bv = biassum[d * 1024 + gblk * 64 + ct * 16 + (l & 15)];
    acc[ct][0] = bv; acc[ct][1] = bv; acc[ct][2] = bv; acc[ct][3] = bv;
  }

  const int arow = w * 16 + (l & 15);
#pragma unroll
  for (int ks = 0; ks < 8; ++ks) {
    int hidx = (arow * 256 + ks * 32 + (l >> 4) * 8) ^ ((arow & 7) << 3);
    half8 af = *(const half8*)&xs[hidx];
#pragma unroll
    for (int ct = 0; ct < 4; ++ct)
      acc[ct] = mfma16(af, Bf[ct][ks], acc[ct]);
  }

#pragma unroll
  for (int ct = 0; ct < 4; ++ct) {
    ushort4 sv;
    sv.x = __half_as_ushort(__float2half(acc[ct][0]));
    sv.y = __half_as_ushort(__float2half(acc[ct][1]));
    sv.z = __half_as_ushort(__float2half(acc[ct][2]));
    sv.w = __half_as_ushort(__float2half(acc[ct][3]));
    size_t base = ((size_t)(ls * 4 + w) * 64 + (gblk * 4 + ct)) * 256 + l * 4;
    *(ushort4*)((unsigned short*)xg + base) = sv;
  }
}

// ---------------------------------------------------------------------------
// Distributed persistent LSTM scan (r10/r12 configuration — empirical floor
// of the 4-partner L3-atomic exchange family: 307us/dispatch).
// grid (32): id = ug*8 + grp, grp = d*4+bg (4 exchange partners share grp).
// 2 barriers/step (dbuf h), b64 atomics, publish-only vmcnt drain, per-wave
// 3-lane busy poll fused with the pull, outb/xg-prefetch after the flag store.
// ---------------------------------------------------------------------------
__global__ __launch_bounds__(512, 2) void scan_dist4(
    int c, const __half* __restrict__ xgF, const __half* __restrict__ xgB,
    const __half* __restrict__ whhfrag,
    const float* __restrict__ hin, const float* __restrict__ cin,
    float* __restrict__ hstate, float* __restrict__ cstate,
    __half* __restrict__ outb, unsigned long long* __restrict__ hexu,
    int* __restrict__ flags)
{
  const int id = blockIdx.x;
  const int ug = id >> 3, grp = id & 7;
  const int d = grp >> 2, bg = grp & 3;
  const int tid = threadIdx.x, w = tid >> 6, l = tid & 63;
  const int m = l & 15, qr = l >> 4, q = m & 3, ul = m >> 2;
  const unsigned short* xg = (const unsigned short*)(d ? xgB : xgF);

  __shared__ unsigned short hb0[16 * 256];   // 8 KB (double buffer)
  __shared__ unsigned short hb1[16 * 256];   // 8 KB

  const int pf0 = ug * 16 + w * 2;

  // Whh fragments, VGPR-resident (64 VGPR)
  half8 Wf[2][8];
#pragma unroll
  for (int cf = 0; cf < 2; ++cf)
#pragma unroll
    for (int ks = 0; ks < 8; ++ks)
      Wf[cf][ks] = *(const half8*)(whhfrag +
          ((size_t)(d * 64 + pf0 + cf) * 8 + ks) * 512 + l * 8);

  // stage h_in into hb0, c_in into regs
#pragma unroll
  for (int i = 0; i < 8; ++i) {
    int idx = i * 512 + tid;
    int r = idx >> 8, u = idx & 255;
    hb0[HSWZ(r, u)] = __half_as_ushort(
        __float2half(hin[(size_t)(d * BB + bg * 16 + r) * HH + u]));
  }
  float cst[2][4];
#pragma unroll
  for (int cf = 0; cf < 2; ++cf) {
    int U = (pf0 + cf) * 4 + ul;
#pragma unroll
    for (int j = 0; j < 4; ++j)
      cst[cf][j] = cin[(size_t)(d * BB + bg * 16 + qr * 4 + j) * HH + U];
  }
  __syncthreads();

  int afo[8];
#pragma unroll
  for (int ks = 0; ks < 8; ++ks) afo[ks] = HSWZ(m, ks * 32 + qr * 8);
  const int kso0 = ug * 2, kso1 = ug * 2 + 1;

  const unsigned short* xp = xg + ((size_t)bg * 64 + pf0) * 256 + l * 4;
  const float actB = (q == 2) ? 2.f : 1.f;

  // prologue: C-init + own-ks for step 0 (reads hb0)
  f32x4 acc[2];
  {
    ushort4 xv0[2];
#pragma unroll
    for (int cf = 0; cf < 2; ++cf) xv0[cf] = *(const ushort4*)(xp + cf * 256);
#pragma unroll
    for (int cf = 0; cf < 2; ++cf) {
      acc[cf][0] = __half2float(__ushort_as_half(xv0[cf].x));
      acc[cf][1] = __half2float(__ushort_as_half(xv0[cf].y));
      acc[cf][2] = __half2float(__ushort_as_half(xv0[cf].z));
      acc[cf][3] = __half2float(__ushort_as_half(xv0[cf].w));
    }
    half8 ao0 = *(const half8*)&hb0[afo[kso0]];
    half8 ao1 = *(const half8*)&hb0[afo[kso1]];
#pragma unroll
    for (int cf = 0; cf < 2; ++cf) {
      acc[cf] = mfma16(ao0, Wf[cf][kso0], acc[cf]);
      acc[cf] = mfma16(ao1, Wf[cf][kso1], acc[cf]);
    }
  }
  ushort4 xv[2];   // xg(ls+1)
#pragma unroll
  for (int cf = 0; cf < 2; ++cf)
    xv[cf] = *(const ushort4*)(xp + (size_t)65536 + cf * 256);

  int p = 0;
  for (int ls = 0; ls < CH; ++ls) {
    unsigned short* cur = p ? hb1 : hb0;
    unsigned short* nxt = p ? hb0 : hb1;
    int tA = c * CH + ls;
    if (d) tA = TT - 1 - tA;
    unsigned long long* hx = hexu + (size_t)(grp * 2 + (ls & 1)) * 1024;

    // peer A-frags from cur (no barrier needed: writes go to nxt)
    half8 afp[6];
#pragma unroll
    for (int i = 0; i < 6; ++i) {
      int ks = i + (i >= kso0 ? 2 : 0);
      afp[i] = *(const half8*)&cur[afo[ks]];
    }
#pragma unroll
    for (int i = 0; i < 6; ++i) {
      int ks = i + (i >= kso0 ? 2 : 0);
#pragma unroll
      for (int cf = 0; cf < 2; ++cf)
        acc[cf] = mfma16(afp[i], Wf[cf][ks], acc[cf]);
    }

    // slim epilogue; q==0 lanes own the combined result; publish b64
#pragma unroll
    for (int cf = 0; cf < 2; ++cf) {
      f32x4 a0;
#pragma unroll
      for (int jj = 0; jj < 4; ++jj) {
        float e = __expf(actB * acc[cf][jj]);
        a0[jj] = 1.f - __fdividef(actB, e + 1.f);
      }
      f32x4 a1 = shflx4(a0, 1);
      f32x4 a2 = shflx4(a0, 2);
      f32x4 a3 = shflx4(a0, 3);
      const int U = (pf0 + cf) * 4 + ul;
      float hv[4];
#pragma unroll
      for (int jj = 0; jj < 4; ++jj) {
        float cn = a1[jj] * cst[cf][jj] + a0[jj] * a2[jj];
        cst[cf][jj] = cn;
        float e2 = __expf(2.f * cn);
        hv[jj] = a3[jj] * (1.f - __fdividef(2.f, e2 + 1.f));
      }
      if (q == 0) {
        unsigned int p0 = (unsigned int)__half_as_ushort(__float2half(hv[0])) |
            ((unsigned int)__half_as_ushort(__float2half(hv[1])) << 16);
        unsigned int p1 = (unsigned int)__half_as_ushort(__float2half(hv[2])) |
            ((unsigned int)__half_as_ushort(__float2half(hv[3])) << 16);
        nxt[HSWZ(qr * 4 + 0, U)] = (unsigned short)(p0 & 0xffff);
        nxt[HSWZ(qr * 4 + 1, U)] = (unsigned short)(p0 >> 16);
        nxt[HSWZ(qr * 4 + 2, U)] = (unsigned short)(p1 & 0xffff);
        nxt[HSWZ(qr * 4 + 3, U)] = (unsigned short)(p1 >> 16);
        unsigned long long pk =
            (unsigned long long)p0 | ((unsigned long long)p1 << 32);
        __hip_atomic_store(&hx[U * 4 + qr], pk, __ATOMIC_RELAXED,
                           __HIP_MEMORY_SCOPE_AGENT);
      }
    }
    asm volatile("s_waitcnt vmcnt(0)" ::: "memory");  // only publish in flight
    __syncthreads();   // B_b: nxt own slice complete; all publishes drained

    const int fbase = ((grp * NCH + c) * CH + ls) * 32;
    if (tid == 0)
      __hip_atomic_store(&flags[fbase + ug], 1, __ATOMIC_RELAXED,
                         __HIP_MEMORY_SCOPE_AGENT);

    // ---- overlapped, peer-independent work ----
    {
      const int pr = tid >> 5, uL2 = (tid & 31) * 2;
      const int u = ug * 64 + uL2;
      *(unsigned int*)&outb[((size_t)tA * BB + bg * 16 + pr) * DD + d * HH + u] =
          *(const unsigned int*)&nxt[HSWZ(pr, u)];
    }
#pragma unroll
    for (int cf = 0; cf < 2; ++cf) {
      acc[cf][0] = __half2float(__ushort_as_half(xv[cf].x));
      acc[cf][1] = __half2float(__ushort_as_half(xv[cf].y));
      acc[cf][2] = __half2float(__ushort_as_half(xv[cf].z));
      acc[cf][3] = __half2float(__ushort_as_half(xv[cf].w));
    }
    {
      half8 ao0 = *(const half8*)&nxt[afo[kso0]];
      half8 ao1 = *(const half8*)&nxt[afo[kso1]];
#pragma unroll
      for (int cf = 0; cf < 2; ++cf) {
        acc[cf] = mfma16(ao0, Wf[cf][kso0], acc[cf]);
        acc[cf] = mfma16(ao1, Wf[cf][kso1], acc[cf]);
      }
    }
    {
      int lsn = (ls + 2 < CH) ? ls + 2 : CH - 1;
      const unsigned short* xn = xp + (size_t)lsn * 65536;
#pragma unroll
      for (int cf = 0; cf < 2; ++cf)
        xv[cf] = *(const ushort4*)(xn + cf * 256);
    }

    // ---- per-wave busy poll (3 lanes), then pull immediately ----
    {
      bool need = (l < 4) && (l != ug);
      int got = need ? 0 : 1;
      while (!__all(got != 0)) {
        if (need && !got)
          got = __hip_atomic_load(&flags[fbase + l], __ATOMIC_RELAXED,
                                  __HIP_MEMORY_SCOPE_AGENT);
      }
    }
#pragma unroll
    for (int rep = 0; rep < 2; ++rep) {
      int idx = tid + rep * 512;
      if (idx < 768) {
        int pi = idx >> 8, rem = idx & 255, uu = rem >> 2, rq = rem & 3;
        int peer = pi + (pi >= ug ? 1 : 0);
        int U = peer * 64 + uu;
        unsigned long long v =
            __hip_atomic_load(&hx[U * 4 + rq], __ATOMIC_RELAXED,
                              __HIP_MEMORY_SCOPE_AGENT);
        nxt[HSWZ(rq * 4 + 0, U)] = (unsigned short)(v & 0xffff);
        nxt[HSWZ(rq * 4 + 1, U)] = (unsigned short)((v >> 16) & 0xffff);
        nxt[HSWZ(rq * 4 + 2, U)] = (unsigned short)((v >> 32) & 0xffff);
        nxt[HSWZ(rq * 4 + 3, U)] = (unsigned short)(v >> 48);
      }
    }
    __syncthreads();   // B_d: nxt = h(ls+1) complete
    p ^= 1;
  }

  // final states (h in hb[p], c in regs)
  {
    unsigned short* fin = p ? hb1 : hb0;
#pragma unroll
    for (int i = 0; i < 8; ++i) {
      int idx = i * 512 + tid;
      int r = idx >> 8, u = idx & 255;
      hstate[(size_t)(d * BB + bg * 16 + r) * HH + u] =
          __half2float(__ushort_as_half(fin[HSWZ(r, u)]));
    }
  }
  if (q == 0) {
#pragma unroll
    for (int cf = 0; cf < 2; ++cf) {
      int U = (pf0 + cf) * 4 + ul;
#pragma unroll
      for (int j = 0; j < 4; ++j)
        cstate[(size_t)(d * BB + bg * 16 + qr * 4 + j) * HH + U] = cst[cf][j];
    }
  }
}

// ---------------------------------------------------------------------------
// squish+logits via MFMA (validated r11/r12: absmax unchanged at 4.88e-4)
// ---------------------------------------------------------------------------
__global__ __launch_bounds__(256, 1) void squish_mfma(
    const __half* __restrict__ outb, const __half* __restrict__ wwfrag,
    const float* __restrict__ bw, const float* __restrict__ proj,
    float* __restrict__ logits)
{
  const int r0 = blockIdx.x * 64;
  const int tid = threadIdx.x, w = tid >> 6, l = tid & 63;
  const int m = l & 15, qr = l >> 4;

  f32x4 acc[32];
#pragma unroll
  for (int cf = 0; cf < 32; ++cf) {
    acc[cf][0] = 0.f; acc[cf][1] = 0.f; acc[cf][2] = 0.f; acc[cf][3] = 0.f;
  }

  const unsigned short* arow =
      (const unsigned short*)outb + (size_t)(r0 + w * 16 + m) * DD + qr * 8;
  const __half* bfb = wwfrag + l * 8;

#pragma unroll
  for (int ks = 0; ks < 16; ++ks) {
    half8 a = *(const half8*)(arow + ks * 32);
#pragma unroll
    for (int cf = 0; cf < 32; ++cf) {
      half8 b = *(const half8*)(bfb + (size_t)(cf * 16 + ks) * 512);
      acc[cf] = mfma16(a, b, acc[cf]);
    }
  }

  float partial[4] = {0.f, 0.f, 0.f, 0.f};
#pragma unroll
  for (int cf = 0; cf < 32; ++cf) {
    int e = cf * 16 + m;
    float bwv = bw[e], pv = proj[e];
#pragma unroll
    for (int r = 0; r < 4; ++r)
      partial[r] += tanh_(acc[cf][r] + bwv) * pv;
  }
#pragma unroll
  for (int mask = 1; mask < 16; mask <<= 1)
#pragma unroll
    for (int r = 0; r < 4; ++r)
      partial[r] += __shfl_xor(partial[r], mask, 64);
  if (m == 0) {
#pragma unroll
    for (int r = 0; r < 4; ++r)
      logits[r0 + w * 16 + qr * 4 + r] = partial[r];
  }
}

// ---------------------------------------------------------------------------
__global__ __launch_bounds__(256) void softmax_t(const float* __restrict__ logits,
                                                 float* __restrict__ attn)
{
  const int b = blockIdx.x;
  const int tid = threadIdx.x;
  __shared__ float sm[256];
  float v0 = logits[tid * BB + b];
  float v1 = logits[(tid + 256) * BB + b];
  sm[tid] = fmaxf(v0, v1);
  __syncthreads();
  for (int s = 128; s > 0; s >>= 1) {
    if (tid < s) sm[tid] = fmaxf(sm[tid], sm[tid + s]);
    __syncthreads();
  }
  float M = sm[0];
  __syncthreads();
  float e0 = expf(v0 - M), e1 = expf(v1 - M);
  sm[tid] = e0 + e1;
  __syncthreads();
  for (int s = 128; s > 0; s >>= 1) {
    if (tid < s) sm[tid] += sm[tid + s];
    __syncthreads();
  }
  float inv = 1.f / sm[0];
  attn[tid * BB + b] = e0 * inv;
  attn[(tid + 256) * BB + b] = e1 * inv;
}

// ---------------------------------------------------------------------------
__global__ __launch_bounds__(512) void vec_final(
    const __half* __restrict__ outb, const float* __restrict__ attn,
    const float* __restrict__ linW, const float* __restrict__ linb,
    float* __restrict__ y)
{
  const int b = blockIdx.x;
  const int d = threadIdx.x;
  float acc = 0.f;
  for (int t = 0; t < TT; ++t)
    acc += attn[t * BB + b] * __half2float(outb[((size_t)t * BB + b) * DD + d]);
  __shared__ float red[512];
  for (int cls = 0; cls < NCLS; ++cls) {
    red[d] = acc * linW[cls * DD + d];
    __syncthreads();
    for (int s = 256; s > 0; s >>= 1) {
      if (d < s) red[d] += red[d + s];
      __syncthreads();
    }
    if (d == 0) y[b * NCLS + cls] = red[0] + linb[cls];
    __syncthreads();
  }
}

// ---------------------------------------------------------------------------
extern "C" void kernel_launch(void* const* d_in, const int* in_sizes, int n_in,
                              void* d_out, int out_size, void* d_ws, size_t ws_size,
                              hipStream_t stream) {
  const int*   embed     = (const int*)d_in[0];
  const float* h0        = (const float*)d_in[1];
  const float* c0        = (const float*)d_in[2];
  const float* emb_table = (const float*)d_in[3];
  const float* Wih_f     = (const float*)d_in[4];
  const float* Whh_f     = (const float*)d_in[5];
  const float* bih_f     = (const float*)d_in[6];
  const float* bhh_f     = (const float*)d_in[7];
  const float* Wih_b     = (const float*)d_in[8];
  const float* Whh_b     = (const float*)d_in[9];
  const float* bih_b     = (const float*)d_in[10];
  const float* bhh_b     = (const float*)d_in[11];
  const float* W_word    = (const float*)d_in[12];
  const float* b_word    = (const float*)d_in[13];
  const float* proj_word = (const float*)d_in[14];
  const float* lin_W     = (const float*)d_in[15];
  const float* lin_b     = (const float*)d_in[16];

  char* ws = (char*)d_ws;
  __half* xgF     = (__half*)(ws + OFF_XGF);
  __half* xgB     = (__half*)(ws + OFF_XGB);
  __half* outb    = (__half*)(ws + OFF_OUTB);
  __half* whhfrag = (__half*)(ws + OFF_WHHF);
  __half* wihfrag = (__half*)(ws + OFF_WIHF);
  float*  biassum = (float*)(ws + OFF_BIAS);
  float*  hstate  = (float*)(ws + OFF_HST);
  float*  cstate  = (float*)(ws + OFF_CST);
  float*  logits  = (float*)(ws + OFF_LOG);
  float*  attn    = (float*)(ws + OFF_ATT);
  unsigned long long* hexu = (unsigned long long*)(ws + OFF_HEX);
  int*    flags   = (int*)(ws + OFF_FLG);
  __half* wwfrag  = (__half*)(ws + OFF_WWF);

  // zero the exchange flags every launch (deterministic; graph-capturable)
  hipMemsetAsync(flags, 0, 524288, stream);

  make_frags<<<4096, 256, 0, stream>>>(Whh_f, Whh_b, Wih_f, Wih_b, whhfrag, wihfrag);
  make_wwfrag<<<1024, 256, 0, stream>>>(W_word, wwfrag);
  bias_prep<<<8, 256, 0, stream>>>(bih_f, bhh_f, bih_b, bhh_b, biassum);

  for (int c = 0; c < NCH; ++c) {
    xg_mfma<<<dim3(CH, 16, 2), 256, 0, stream>>>(c, embed, emb_table,
        wihfrag, biassum, xgF, xgB);
    const float* hin = (c == 0) ? h0 : hstate;
    const float* cin = (c == 0) ? c0 : cstate;
    scan_dist4<<<dim3(32), 512, 0, stream>>>(c, xgF, xgB, whhfrag,
        hin, cin, hstate, cstate, outb, hexu, flags);
  }

  squish_mfma<<<512, 256, 0, stream>>>(outb, wwfrag, b_word, proj_word, logits);
  softmax_t<<<64, 256, 0, stream>>>(logits, attn);
  vec_final<<<64, 512, 0, stream>>>(outb, attn, lin_W, lin_b, (float*)d_out);
}